// Round 7
// baseline (69.338 us; speedup 1.0000x reference)
//
#include <hip/hip_runtime.h>
#include <stdint.h>

// Problem constants (match reference setup_inputs)
#define BATCH   8
#define CIMG    3
#define HFULL   512
#define WFULL   512
#define HWFULL  (HFULL * WFULL)          // 262144
#define CFEAT   64
#define HE      128
#define WE      128
#define HWE     (HE * WE)                // 16384
#define NSEG    64
#define NBSEG   (BATCH * NSEG)           // 512
#define WALL_COT 0.5f
#define MIN_FRAC 0.01f

#define NBLK    1024                     // 1024 blocks x 512 threads
#define BLKT    512
#define NWAVE   8
#define NREP    8                        // replicated global bin sets

// ws layout (floats unless noted):
// [0 .. 12288)   replicated bins: per rep (stride 1536) { cnt[512] | sum[512] | pos[512] }
// [12288]        completion counter (as unsigned)
// [12292..13316) per-block recovery numerator   (agent stores)
// [13316..14340) per-block recovery denominator (agent stores)
#define WS_BINS_FLOATS (NREP * 3 * NBSEG)            // 12288
#define WS_CTR   WS_BINS_FLOATS                      // 12288
#define WS_BNUM  (WS_CTR + 4)                        // 12292
#define WS_BDEN  (WS_BNUM + NBLK)                    // 13316
#define WS_ZERO_FLOATS (WS_CTR + 1)                  // bins + counter

__device__ __forceinline__ float agent_load(const float* p) {
    return __hip_atomic_load(p, __ATOMIC_RELAXED, __HIP_MEMORY_SCOPE_AGENT);
}
__device__ __forceinline__ void agent_store(float* p, float v) {
    __hip_atomic_store(p, v, __ATOMIC_RELAXED, __HIP_MEMORY_SCOPE_AGENT);
}

__global__ __launch_bounds__(BLKT) void confloss_fused_kernel(
    const float* __restrict__ outputs, const float* __restrict__ inputs,
    const float* __restrict__ enc1,    const float* __restrict__ dec1,
    const float* __restrict__ masks,   const int* __restrict__ segs,
    float* __restrict__ ws, float* __restrict__ out)
{
    const int tid = threadIdx.x;
    const int w   = tid >> 6;            // wave id [0,8)
    const int l   = tid & 63;            // lane id
    const int i   = blockIdx.x * BLKT + tid;

    // per-wave LDS bin replicas -> no cross-wave races, no early barrier
    __shared__ float s_sumW[NWAVE][NSEG];
    __shared__ float s_cntW[NWAVE][NSEG];
    __shared__ float s_posW[NWAVE][NSEG];
    __shared__ float s_rn[NWAVE], s_rd[NWAVE];
    __shared__ int   s_last;
    s_sumW[w][l] = 0.f; s_cntW[w][l] = 0.f; s_posW[w][l] = 0.f;

    // ---- A-task decode: px-group g (4 px), 4-channel slice c ----
    const int g  = i & 32767;            // [0,32768): 8 batches x 4096 groups
    const int c  = i >> 15;              // [0,16): block-uniform
    const int ba = g >> 12;              // batch (block-uniform)
    const int ra = (g & 4095) * 4;       // px offset in 128x128 plane
    const size_t abase = ((size_t)ba * CFEAT + (size_t)c * 4) * HWE + ra;
    const float* ep = enc1 + abase;
    const float* dp = dec1 + abase;

    // ---- B-task decode: 4 full-res px ----
    const int bb = i >> 16;              // block-uniform
    const int rb = (i & 65535) * 4;
    const float* ob = outputs + (size_t)bb * (CIMG * HWFULL) + rb;
    const float* ib = inputs  + (size_t)bb * (CIMG * HWFULL) + rb;

    // ---- loads (compiler schedules; proven equivalent to pinned variants) ----
    const float4 e0 = *(const float4*)(ep);
    const float4 e1 = *(const float4*)(ep + HWE);
    const float4 e2 = *(const float4*)(ep + 2 * HWE);
    const float4 e3 = *(const float4*)(ep + 3 * HWE);
    const float4 d0 = *(const float4*)(dp);
    const float4 d1 = *(const float4*)(dp + HWE);
    const float4 d2 = *(const float4*)(dp + 2 * HWE);
    const float4 d3 = *(const float4*)(dp + 3 * HWE);
    const float4 mB = *(const float4*)(masks + (size_t)bb * HWFULL + rb);
    const float4 o0 = *(const float4*)(ob);
    const float4 o1 = *(const float4*)(ob + HWFULL);
    const float4 o2 = *(const float4*)(ob + 2 * HWFULL);
    const float4 i0 = *(const float4*)(ib);
    const float4 i1 = *(const float4*)(ib + HWFULL);
    const float4 i2 = *(const float4*)(ib + 2 * HWFULL);

    // scattered seg/mask gather at nearest-neighbor full-res positions
    const int ya = ra >> 7, xa = ra & (WE - 1);
    const int fb = ba * HWFULL + (ya * 4) * WFULL + xa * 4;
    const int s0 = segs[fb], s1 = segs[fb + 4], s2 = segs[fb + 8], s3 = segs[fb + 12];
    const bool duty = (c == (g & 15));   // exactly one c-slice counts each px-group
    float mk0 = 1.f, mk1 = 1.f, mk2 = 1.f, mk3 = 1.f;
    if (duty) {
        mk0 = masks[fb];     mk1 = masks[fb + 4];
        mk2 = masks[fb + 8]; mk3 = masks[fb + 12];
    }

    // ---- B consume: recovery loss partials ----
    float num = 0.f, den = 0.f;
    {
        float tgt, dd, mse;
        mse = 0.f;
        tgt = (mB.x >= WALL_COT) ? 0.f : i0.x; dd = o0.x - tgt; mse += dd * dd;
        tgt = (mB.x >= WALL_COT) ? 0.f : i1.x; dd = o1.x - tgt; mse += dd * dd;
        tgt = (mB.x >= WALL_COT) ? 0.f : i2.x; dd = o2.x - tgt; mse += dd * dd;
        if (mB.x > 0.f) { num += mse; den += 1.f; }
        mse = 0.f;
        tgt = (mB.y >= WALL_COT) ? 0.f : i0.y; dd = o0.y - tgt; mse += dd * dd;
        tgt = (mB.y >= WALL_COT) ? 0.f : i1.y; dd = o1.y - tgt; mse += dd * dd;
        tgt = (mB.y >= WALL_COT) ? 0.f : i2.y; dd = o2.y - tgt; mse += dd * dd;
        if (mB.y > 0.f) { num += mse; den += 1.f; }
        mse = 0.f;
        tgt = (mB.z >= WALL_COT) ? 0.f : i0.z; dd = o0.z - tgt; mse += dd * dd;
        tgt = (mB.z >= WALL_COT) ? 0.f : i1.z; dd = o1.z - tgt; mse += dd * dd;
        tgt = (mB.z >= WALL_COT) ? 0.f : i2.z; dd = o2.z - tgt; mse += dd * dd;
        if (mB.z > 0.f) { num += mse; den += 1.f; }
        mse = 0.f;
        tgt = (mB.w >= WALL_COT) ? 0.f : i0.w; dd = o0.w - tgt; mse += dd * dd;
        tgt = (mB.w >= WALL_COT) ? 0.f : i1.w; dd = o1.w - tgt; mse += dd * dd;
        tgt = (mB.w >= WALL_COT) ? 0.f : i2.w; dd = o2.w - tgt; mse += dd * dd;
        if (mB.w > 0.f) { num += mse; den += 1.f; }
    }

    // ---- A consume: per-px 4-channel error partials into own wave's bins ----
    {
        float t0, t1, t2, t3;
        t0 = e0.x - d0.x; t1 = e1.x - d1.x; t2 = e2.x - d2.x; t3 = e3.x - d3.x;
        const float p0 = (t0*t0 + t1*t1 + t2*t2 + t3*t3) * (1.0f / (float)CFEAT);
        t0 = e0.y - d0.y; t1 = e1.y - d1.y; t2 = e2.y - d2.y; t3 = e3.y - d3.y;
        const float p1 = (t0*t0 + t1*t1 + t2*t2 + t3*t3) * (1.0f / (float)CFEAT);
        t0 = e0.z - d0.z; t1 = e1.z - d1.z; t2 = e2.z - d2.z; t3 = e3.z - d3.z;
        const float p2 = (t0*t0 + t1*t1 + t2*t2 + t3*t3) * (1.0f / (float)CFEAT);
        t0 = e0.w - d0.w; t1 = e1.w - d1.w; t2 = e2.w - d2.w; t3 = e3.w - d3.w;
        const float p3 = (t0*t0 + t1*t1 + t2*t2 + t3*t3) * (1.0f / (float)CFEAT);

        atomicAdd(&s_sumW[w][s0], p0);
        atomicAdd(&s_sumW[w][s1], p1);
        atomicAdd(&s_sumW[w][s2], p2);
        atomicAdd(&s_sumW[w][s3], p3);
        if (duty) {
            atomicAdd(&s_cntW[w][s0], 1.f); if (mk0 > 0.f && mk0 < WALL_COT) atomicAdd(&s_posW[w][s0], 1.f);
            atomicAdd(&s_cntW[w][s1], 1.f); if (mk1 > 0.f && mk1 < WALL_COT) atomicAdd(&s_posW[w][s1], 1.f);
            atomicAdd(&s_cntW[w][s2], 1.f); if (mk2 > 0.f && mk2 < WALL_COT) atomicAdd(&s_posW[w][s2], 1.f);
            atomicAdd(&s_cntW[w][s3], 1.f); if (mk3 > 0.f && mk3 < WALL_COT) atomicAdd(&s_posW[w][s3], 1.f);
        }
    }

    // ---- B wave reduce ----
#pragma unroll
    for (int off = 32; off >= 1; off >>= 1) {
        num += __shfl_down(num, off);
        den += __shfl_down(den, off);
    }
    if (l == 0) { s_rn[w] = num; s_rd[w] = den; }

    __syncthreads();   // single join: LDS bins + s_rn complete

    // ---- block flush to global ----
    if (tid < NSEG) {
        float sv = 0.f, cv = 0.f, pv = 0.f;
#pragma unroll
        for (int k = 0; k < NWAVE; ++k) {
            sv += s_sumW[k][tid]; cv += s_cntW[k][tid]; pv += s_posW[k][tid];
        }
        const int rep = blockIdx.x & (NREP - 1);
        float* bins = ws + rep * (3 * NBSEG);
        const int gb = ba * NSEG + tid;
        if (cv != 0.f) atomicAdd(&bins[gb], cv);
        if (sv != 0.f) atomicAdd(&bins[NBSEG + gb], sv);
        if (pv != 0.f) atomicAdd(&bins[2 * NBSEG + gb], pv);
    }
    if (tid == 0) {
        float tn = 0.f, td = 0.f;
#pragma unroll
        for (int k = 0; k < NWAVE; ++k) { tn += s_rn[k]; td += s_rd[k]; }
        agent_store(&ws[WS_BNUM + blockIdx.x], tn);
        agent_store(&ws[WS_BDEN + blockIdx.x], td);
    }
    __syncthreads();   // drains each wave's global ops (vmcnt) before handshake

    if (tid == 0) {
        __threadfence();
        unsigned* ctr = (unsigned*)(ws + WS_CTR);
        const unsigned old = atomicAdd(ctr, 1u);
        s_last = (old == NBLK - 1) ? 1 : 0;
    }
    __syncthreads();

    if (s_last) {
        // ---- inline finalize: this block sees all bins complete ----
        const int t = tid;   // [0,512): one (b,seg) each
        float cnt = 0.f, sum = 0.f, pos = 0.f;
#pragma unroll
        for (int rep = 0; rep < NREP; ++rep) {
            const float* bins = ws + rep * (3 * NBSEG);
            cnt += agent_load(&bins[t]);
            sum += agent_load(&bins[NBSEG + t]);
            pos += agent_load(&bins[2 * NBSEG + t]);
        }
        float rn = 0.f, rd = 0.f;
#pragma unroll
        for (int k = 0; k < NBLK / BLKT; ++k) {
            rn += agent_load(&ws[WS_BNUM + t + k * BLKT]);
            rd += agent_load(&ws[WS_BDEN + t + k * BLKT]);
        }
        const float safe = fmaxf(cnt, 1.0f);
        const float mean = sum / safe;
        const bool valid = (cnt / (float)HWE) >= MIN_FRAC;
        const bool posf  = (pos / safe) > MIN_FRAC;
        float sel = (valid && posf) ? 1.0f : 0.0f;
        float val = mean * sel;

#pragma unroll
        for (int off = 32; off >= 1; off >>= 1) {
            val += __shfl_down(val, off);
            sel += __shfl_down(sel, off);
            rn  += __shfl_down(rn,  off);
            rd  += __shfl_down(rd,  off);
        }
        __shared__ float fv[NWAVE], fs[NWAVE], fn[NWAVE], fd[NWAVE];
        if (l == 0) { fv[w] = val; fs[w] = sel; fn[w] = rn; fd[w] = rd; }
        __syncthreads();
        if (tid == 0) {
            float tv = 0.f, ts = 0.f, tn = 0.f, td = 0.f;
#pragma unroll
            for (int k = 0; k < NWAVE; ++k) { tv += fv[k]; ts += fs[k]; tn += fn[k]; td += fd[k]; }
            const float flat_pos_mean = tv / fmaxf(ts, 1.0f);
            const float loss_recov = tn / fmaxf(td, 1.0f);
            out[0] = loss_recov + flat_pos_mean;
        }
    }
}

extern "C" void kernel_launch(void* const* d_in, const int* in_sizes, int n_in,
                              void* d_out, int out_size, void* d_ws, size_t ws_size,
                              hipStream_t stream) {
    const float* outputs = (const float*)d_in[0];
    const float* inputs  = (const float*)d_in[1];
    const float* enc1    = (const float*)d_in[2];
    const float* dec1    = (const float*)d_in[3];
    const float* masks   = (const float*)d_in[4];
    const int*   segs    = (const int*)d_in[5];
    float* ws  = (float*)d_ws;
    float* out = (float*)d_out;

    // zero atomic bins + completion counter every call
    hipMemsetAsync(ws, 0, WS_ZERO_FLOATS * sizeof(float), stream);

    confloss_fused_kernel<<<NBLK, BLKT, 0, stream>>>(
        outputs, inputs, enc1, dec1, masks, segs, ws, out);
}

// Round 8
// 34.819 us; speedup vs baseline: 1.9914x; 1.9914x over previous
//
#include <hip/hip_runtime.h>
#include <stdint.h>

// Problem constants (match reference setup_inputs)
#define BATCH   8
#define CIMG    3
#define HFULL   512
#define WFULL   512
#define HWFULL  (HFULL * WFULL)          // 262144
#define CFEAT   64
#define HE      128
#define WE      128
#define HWE     (HE * WE)                // 16384
#define NSEG    64
#define NBSEG   (BATCH * NSEG)           // 512
#define WALL_COT 0.5f
#define MIN_FRAC 0.01f

#define NBLK    1024                     // 1024 blocks x 256 threads, 2 stages/thread
#define NREP    8                        // replicated global bin sets

// ws float layout:
// [0 .. 12288)        replicated bins: per rep { cnt[512] | sum[512] | pos[512] }
// [12288 .. 13312)    per-block recovery numerator   (plain store)
// [13312 .. 14336)    per-block recovery denominator (plain store)
#define WS_BINS_FLOATS (NREP * 3 * NBSEG)            // 12288
#define WS_BNUM  WS_BINS_FLOATS
#define WS_BDEN  (WS_BNUM + NBLK)
#define WS_ZERO_FLOATS WS_BINS_FLOATS

// native clang vector types: swizzle-capable AND valid "v" asm operands
typedef float vf4 __attribute__((ext_vector_type(4)));

__global__ __launch_bounds__(256) void confloss_main_kernel(
    const float* __restrict__ outputs, const float* __restrict__ inputs,
    const float* __restrict__ enc1,    const float* __restrict__ dec1,
    const float* __restrict__ masks,   const int* __restrict__ segs,
    float* __restrict__ ws)
{
    const int tid = threadIdx.x;
    const int w   = tid >> 6;            // wave id [0,4)
    const int l   = tid & 63;            // lane id
    const int i   = blockIdx.x * 256 + tid;   // [0, 262144)

    __shared__ float s_sumW[4][NSEG];    // per-wave sum bins
    __shared__ float s_cnt[NSEG], s_pos[NSEG];
    __shared__ float s_rn[4], s_rd[4];
    s_sumW[w][l] = 0.f;
    if (tid < NSEG) { s_cnt[tid] = 0.f; s_pos[tid] = 0.f; }
    __syncthreads();

    // ---- A decode: stage k handles channel-slice c+8k of the SAME px-group ----
    const int g  = i & 32767;            // px-group [0,32768)
    const int c  = i >> 15;              // [0,8) (stage1 uses c+8); block-uniform
    const int ba = g >> 12;              // batch (block-uniform, same both stages)
    const int ra = (g & 4095) * 4;       // px offset in 128x128 plane
    const size_t abase = ((size_t)ba * CFEAT + (size_t)c * 4) * HWE + ra;
    const float* ep0 = enc1 + abase;
    const float* dp0 = dec1 + abase;
    const float* ep1 = ep0 + (size_t)32 * HWE;   // c+8 -> +32 channels
    const float* dp1 = dp0 + (size_t)32 * HWE;

    // ---- B decode: stage k handles batch bb+4k at the same plane offset ----
    const int bb = i >> 16;              // [0,4); block-uniform
    const int rb = (i & 65535) * 4;
    const float* ob0 = outputs + (size_t)bb * (CIMG * HWFULL) + rb;
    const float* ib0 = inputs  + (size_t)bb * (CIMG * HWFULL) + rb;
    const float* ob1 = ob0 + (size_t)4 * (CIMG * HWFULL);
    const float* ib1 = ib0 + (size_t)4 * (CIMG * HWFULL);
    const float* mp0 = masks + (size_t)bb * HWFULL + rb;
    const float* mp1 = mp0 + (size_t)4 * HWFULL;

    // seg/mask gather (once; shared by both stages)
    const int ya = ra >> 7, xa = ra & (WE - 1);
    const int fb = ba * HWFULL + (ya * 4) * WFULL + xa * 4;
    const int gl = g & 15;
    const bool duty = (gl == c) || (gl == c + 8);  // counted exactly once over all stages

    // ================= STAGE 0 ISSUE =================
    const vf4 e00 = *(const vf4*)(ep0);
    const vf4 e01 = *(const vf4*)(ep0 + HWE);
    const vf4 e02 = *(const vf4*)(ep0 + 2 * HWE);
    const vf4 e03 = *(const vf4*)(ep0 + 3 * HWE);
    const vf4 d00 = *(const vf4*)(dp0);
    const vf4 d01 = *(const vf4*)(dp0 + HWE);
    const vf4 d02 = *(const vf4*)(dp0 + 2 * HWE);
    const vf4 d03 = *(const vf4*)(dp0 + 3 * HWE);
    const vf4 mB0 = *(const vf4*)(mp0);
    const vf4 o00 = *(const vf4*)(ob0);
    const vf4 o01 = *(const vf4*)(ob0 + HWFULL);
    const vf4 o02 = *(const vf4*)(ob0 + 2 * HWFULL);
    const vf4 i00 = *(const vf4*)(ib0);
    const vf4 i01 = *(const vf4*)(ib0 + HWFULL);
    const vf4 i02 = *(const vf4*)(ib0 + 2 * HWFULL);
    const int s0 = segs[fb], s1 = segs[fb + 4], s2 = segs[fb + 8], s3 = segs[fb + 12];
    float mk0 = 1.f, mk1 = 1.f, mk2 = 1.f, mk3 = 1.f;
    if (duty) {
        mk0 = masks[fb];     mk1 = masks[fb + 4];
        mk2 = masks[fb + 8]; mk3 = masks[fb + 12];
    }
    // SINGLE pin consuming every stage-0 value: all loads above must be issued
    // before this point and ALL results simultaneously live (no re-serialization).
    asm volatile("" ::
        "v"(e00), "v"(e01), "v"(e02), "v"(e03),
        "v"(d00), "v"(d01), "v"(d02), "v"(d03),
        "v"(mB0), "v"(o00), "v"(o01), "v"(o02),
        "v"(i00), "v"(i01), "v"(i02));
    asm volatile("" :: "v"(s0), "v"(s1), "v"(s2), "v"(s3),
                       "v"(mk0), "v"(mk1), "v"(mk2), "v"(mk3));

    // ================= STAGE 1 ISSUE (in flight while stage 0 is consumed) ====
    const vf4 e10 = *(const vf4*)(ep1);
    const vf4 e11 = *(const vf4*)(ep1 + HWE);
    const vf4 e12 = *(const vf4*)(ep1 + 2 * HWE);
    const vf4 e13 = *(const vf4*)(ep1 + 3 * HWE);
    const vf4 d10 = *(const vf4*)(dp1);
    const vf4 d11 = *(const vf4*)(dp1 + HWE);
    const vf4 d12 = *(const vf4*)(dp1 + 2 * HWE);
    const vf4 d13 = *(const vf4*)(dp1 + 3 * HWE);
    const vf4 mB1 = *(const vf4*)(mp1);
    const vf4 o10 = *(const vf4*)(ob1);
    const vf4 o11 = *(const vf4*)(ob1 + HWFULL);
    const vf4 o12 = *(const vf4*)(ob1 + 2 * HWFULL);
    const vf4 i10 = *(const vf4*)(ib1);
    const vf4 i11 = *(const vf4*)(ib1 + HWFULL);
    const vf4 i12 = *(const vf4*)(ib1 + 2 * HWFULL);
    asm volatile("" ::
        "v"(e10), "v"(e11), "v"(e12), "v"(e13),
        "v"(d10), "v"(d11), "v"(d12), "v"(d13),
        "v"(mB1), "v"(o10), "v"(o11), "v"(o12),
        "v"(i10), "v"(i11), "v"(i12));

    // ================= CONSUME B (both stages), registers only =================
    float num = 0.f, den = 0.f;
#define BPIX(mv, a0, a1, a2, b0, b1, b2)                                   \
    {                                                                       \
        float tgt, dd, mse = 0.f;                                           \
        tgt = ((mv) >= WALL_COT) ? 0.f : (b0); dd = (a0) - tgt; mse += dd*dd; \
        tgt = ((mv) >= WALL_COT) ? 0.f : (b1); dd = (a1) - tgt; mse += dd*dd; \
        tgt = ((mv) >= WALL_COT) ? 0.f : (b2); dd = (a2) - tgt; mse += dd*dd; \
        if ((mv) > 0.f) { num += mse; den += 1.f; }                         \
    }
    BPIX(mB0.x, o00.x, o01.x, o02.x, i00.x, i01.x, i02.x)
    BPIX(mB0.y, o00.y, o01.y, o02.y, i00.y, i01.y, i02.y)
    BPIX(mB0.z, o00.z, o01.z, o02.z, i00.z, i01.z, i02.z)
    BPIX(mB0.w, o00.w, o01.w, o02.w, i00.w, i01.w, i02.w)
    BPIX(mB1.x, o10.x, o11.x, o12.x, i10.x, i11.x, i12.x)
    BPIX(mB1.y, o10.y, o11.y, o12.y, i10.y, i11.y, i12.y)
    BPIX(mB1.z, o10.z, o11.z, o12.z, i10.z, i11.z, i12.z)
    BPIX(mB1.w, o10.w, o11.w, o12.w, i10.w, i11.w, i12.w)
#undef BPIX

    // ====== CONSUME A: 8 channels per px (stage0 + stage1 merged in regs) ======
    {
        float t0, t1, t2, t3, u0, u1, u2, u3;
#define APIX(f)                                                             \
        t0 = e00.f - d00.f; t1 = e01.f - d01.f;                             \
        t2 = e02.f - d02.f; t3 = e03.f - d03.f;                             \
        u0 = e10.f - d10.f; u1 = e11.f - d11.f;                             \
        u2 = e12.f - d12.f; u3 = e13.f - d13.f;
        APIX(x)
        const float p0 = (t0*t0 + t1*t1 + t2*t2 + t3*t3 +
                          u0*u0 + u1*u1 + u2*u2 + u3*u3) * (1.0f / (float)CFEAT);
        APIX(y)
        const float p1 = (t0*t0 + t1*t1 + t2*t2 + t3*t3 +
                          u0*u0 + u1*u1 + u2*u2 + u3*u3) * (1.0f / (float)CFEAT);
        APIX(z)
        const float p2 = (t0*t0 + t1*t1 + t2*t2 + t3*t3 +
                          u0*u0 + u1*u1 + u2*u2 + u3*u3) * (1.0f / (float)CFEAT);
        APIX(w)
        const float p3 = (t0*t0 + t1*t1 + t2*t2 + t3*t3 +
                          u0*u0 + u1*u1 + u2*u2 + u3*u3) * (1.0f / (float)CFEAT);
#undef APIX
        atomicAdd(&s_sumW[w][s0], p0);
        atomicAdd(&s_sumW[w][s1], p1);
        atomicAdd(&s_sumW[w][s2], p2);
        atomicAdd(&s_sumW[w][s3], p3);
        if (duty) {
            atomicAdd(&s_cnt[s0], 1.f); if (mk0 > 0.f && mk0 < WALL_COT) atomicAdd(&s_pos[s0], 1.f);
            atomicAdd(&s_cnt[s1], 1.f); if (mk1 > 0.f && mk1 < WALL_COT) atomicAdd(&s_pos[s1], 1.f);
            atomicAdd(&s_cnt[s2], 1.f); if (mk2 > 0.f && mk2 < WALL_COT) atomicAdd(&s_pos[s2], 1.f);
            atomicAdd(&s_cnt[s3], 1.f); if (mk3 > 0.f && mk3 < WALL_COT) atomicAdd(&s_pos[s3], 1.f);
        }
    }

    // ---- B wave reduce -> per-block partial (plain store) ----
#pragma unroll
    for (int off = 32; off >= 1; off >>= 1) {
        num += __shfl_down(num, off);
        den += __shfl_down(den, off);
    }
    if (l == 0) { s_rn[w] = num; s_rd[w] = den; }
    __syncthreads();

    if (tid == 0) {
        ws[WS_BNUM + blockIdx.x] = s_rn[0] + s_rn[1] + s_rn[2] + s_rn[3];
        ws[WS_BDEN + blockIdx.x] = s_rd[0] + s_rd[1] + s_rd[2] + s_rd[3];
    }
    if (tid < NSEG) {
        const int rep = blockIdx.x & (NREP - 1);
        float* bins = ws + rep * (3 * NBSEG);
        const int gb = ba * NSEG + tid;
        const float sv = s_sumW[0][tid] + s_sumW[1][tid] + s_sumW[2][tid] + s_sumW[3][tid];
        if (sv != 0.f) atomicAdd(&bins[NBSEG + gb], sv);
        const float cv = s_cnt[tid];
        if (cv != 0.f) atomicAdd(&bins[gb], cv);
        const float pv = s_pos[tid];
        if (pv != 0.f) atomicAdd(&bins[2 * NBSEG + gb], pv);
    }
}

__global__ __launch_bounds__(512) void confloss_finalize_kernel(
    const float* __restrict__ ws, float* __restrict__ out)
{
    const int t = threadIdx.x;   // one per (b,seg); also NBLK/512 B-partials each
    float rn = 0.f, rd = 0.f;
#pragma unroll
    for (int k = 0; k < NBLK / 512; ++k) {
        rn += ws[WS_BNUM + t + k * 512];
        rd += ws[WS_BDEN + t + k * 512];
    }
    float cnt = 0.f, sum = 0.f, pos = 0.f;
#pragma unroll
    for (int rep = 0; rep < NREP; ++rep) {
        const float* bins = ws + rep * (3 * NBSEG);
        cnt += bins[t];
        sum += bins[NBSEG + t];
        pos += bins[2 * NBSEG + t];
    }
    const float safe = fmaxf(cnt, 1.0f);
    const float mean = sum / safe;
    const bool valid = (cnt / (float)HWE) >= MIN_FRAC;
    const bool posf  = (pos / safe) > MIN_FRAC;
    float sel = (valid && posf) ? 1.0f : 0.0f;
    float val = mean * sel;

#pragma unroll
    for (int off = 32; off >= 1; off >>= 1) {
        val += __shfl_down(val, off);
        sel += __shfl_down(sel, off);
        rn  += __shfl_down(rn,  off);
        rd  += __shfl_down(rd,  off);
    }
    __shared__ float sv[8], ss[8], sn[8], sd[8];
    const int wid = t >> 6;
    if ((t & 63) == 0) { sv[wid] = val; ss[wid] = sel; sn[wid] = rn; sd[wid] = rd; }
    __syncthreads();
    if (t == 0) {
        float tv = 0.f, ts = 0.f, tn = 0.f, td = 0.f;
#pragma unroll
        for (int k = 0; k < 8; ++k) { tv += sv[k]; ts += ss[k]; tn += sn[k]; td += sd[k]; }
        const float flat_pos_mean = tv / fmaxf(ts, 1.0f);
        const float loss_recov = tn / fmaxf(td, 1.0f);
        out[0] = loss_recov + flat_pos_mean;
    }
}

extern "C" void kernel_launch(void* const* d_in, const int* in_sizes, int n_in,
                              void* d_out, int out_size, void* d_ws, size_t ws_size,
                              hipStream_t stream) {
    const float* outputs = (const float*)d_in[0];
    const float* inputs  = (const float*)d_in[1];
    const float* enc1    = (const float*)d_in[2];
    const float* dec1    = (const float*)d_in[3];
    const float* masks   = (const float*)d_in[4];
    const int*   segs    = (const int*)d_in[5];
    float* ws  = (float*)d_ws;
    float* out = (float*)d_out;

    // atomic bins must be zeroed every call
    hipMemsetAsync(ws, 0, WS_ZERO_FLOATS * sizeof(float), stream);

    confloss_main_kernel<<<NBLK, 256, 0, stream>>>(
        outputs, inputs, enc1, dec1, masks, segs, ws);
    confloss_finalize_kernel<<<1, 512, 0, stream>>>(ws, out);
}